// Round 3
// baseline (168.143 us; speedup 1.0000x reference)
//
#include <hip/hip_runtime.h>
#include <math.h>

#define L_  8192
#define D_  512
#define E_  8
#define DE_ 4096      // D_*E_
#define C_  256       // number of L-chunks (one block per chunk, 1 block/CU)
#define LC_ 32        // chunk length = L_/C_
#define ST_ 16        // software-pipeline stage width

typedef float f4_t __attribute__((ext_vector_type(4)));

__device__ __forceinline__ float sigmoidf_(float v) {
    return 1.0f / (1.0f + expf(-v));
}

// Pass 1: one block per chunk (1024 threads, 4 chains each). Zero-inbound
// local contribution: s = sum_i b^(LC-1-i) * a * x[c*LC+i, d]
__global__ __launch_bounds__(1024) void ema_pass1(const float* __restrict__ x,
                                                  const float* __restrict__ ld,
                                                  float* __restrict__ contrib) {
    const int c  = blockIdx.x;        // chunk 0..255
    const int g  = threadIdx.x;       // group 0..1023 (4 e-chains per group)
    const int d  = g >> 1;
    const int eb = (g & 1) << 2;

    float a[4], b[4];
#pragma unroll
    for (int e = 0; e < 4; ++e) { a[e] = sigmoidf_(ld[eb + e]); b[e] = 1.0f - a[e]; }

    float s[4] = {0.f, 0.f, 0.f, 0.f};
    const float* xp = x + (size_t)c * LC_ * D_ + d;

    float xs[2][ST_];
#pragma unroll
    for (int j = 0; j < ST_; ++j) xs[0][j] = xp[(size_t)j * D_];

#pragma unroll
    for (int st = 0; st < LC_ / ST_; ++st) {
        if (st + 1 < LC_ / ST_) {
#pragma unroll
            for (int j = 0; j < ST_; ++j)
                xs[(st + 1) & 1][j] = xp[(size_t)((st + 1) * ST_ + j) * D_];
        }
#pragma unroll
        for (int j = 0; j < ST_; ++j) {
            const float xv = xs[st & 1][j];
#pragma unroll
            for (int e = 0; e < 4; ++e) s[e] = fmaf(b[e], s[e], a[e] * xv);
        }
    }
    f4_t r = {s[0], s[1], s[2], s[3]};
    *(f4_t*)(contrib + (size_t)c * DE_ + 4 * g) = r;
}

// Pass 2: per chain, scan the C_ chunk contributions.
// states[0] = x[0, d]; states[c+1] = (1-a)^LC * states[c] + contrib[c]
// states has C_+1 rows so stores need no guard.
__global__ __launch_bounds__(256) void ema_pass2(const float* __restrict__ x,
                                                 const float* __restrict__ ld,
                                                 const float* __restrict__ contrib,
                                                 float* __restrict__ states) {
    const int chain = blockIdx.x * 256 + threadIdx.x;  // 0..4095
    const int d = chain >> 3;
    const int e = chain & 7;
    const float a = sigmoidf_(ld[e]);
    float B = 1.0f - a;
#pragma unroll
    for (int k = 0; k < 5; ++k) B *= B;   // (1-a)^32 = (1-a)^LC_

    float cb[2][ST_];
#pragma unroll
    for (int j = 0; j < ST_; ++j) cb[0][j] = contrib[(size_t)j * DE_ + chain];

    float s = x[d];                        // initial carry = x[0, d]
    states[chain] = s;

#pragma unroll
    for (int gr = 0; gr < C_ / ST_; ++gr) {
        if (gr + 1 < C_ / ST_) {
#pragma unroll
            for (int j = 0; j < ST_; ++j)
                cb[(gr + 1) & 1][j] = contrib[(size_t)((gr + 1) * ST_ + j) * DE_ + chain];
        }
#pragma unroll
        for (int j = 0; j < ST_; ++j) {
            s = fmaf(B, s, cb[gr & 1][j]);
            states[(size_t)(gr * ST_ + j + 1) * DE_ + chain] = s;
        }
    }
}

// Pass 3: one block per chunk, replay from correct inbound state, stream out.
// Block writes a contiguous 512 KB region; x slice (64 KB) read once per block.
__global__ __launch_bounds__(1024) void ema_pass3(const float* __restrict__ x,
                                                  const float* __restrict__ ld,
                                                  const float* __restrict__ states,
                                                  float* __restrict__ out) {
    const int c  = blockIdx.x;
    const int g  = threadIdx.x;
    const int d  = g >> 1;
    const int eb = (g & 1) << 2;

    float a[4], b[4];
#pragma unroll
    for (int e = 0; e < 4; ++e) { a[e] = sigmoidf_(ld[eb + e]); b[e] = 1.0f - a[e]; }

    f4_t y = *(const f4_t*)(states + (size_t)c * DE_ + 4 * g);
    const float* xp = x + (size_t)c * LC_ * D_ + d;
    float* op = out + (size_t)c * LC_ * DE_ + 4 * g;

    float xs[2][ST_];
#pragma unroll
    for (int j = 0; j < ST_; ++j) xs[0][j] = xp[(size_t)j * D_];

#pragma unroll
    for (int st = 0; st < LC_ / ST_; ++st) {
        if (st + 1 < LC_ / ST_) {
#pragma unroll
            for (int j = 0; j < ST_; ++j)
                xs[(st + 1) & 1][j] = xp[(size_t)((st + 1) * ST_ + j) * D_];
        }
#pragma unroll
        for (int j = 0; j < ST_; ++j) {
            const float xv = xs[st & 1][j];
            y.x = fmaf(b[0], y.x, a[0] * xv);
            y.y = fmaf(b[1], y.y, a[1] * xv);
            y.z = fmaf(b[2], y.z, a[2] * xv);
            y.w = fmaf(b[3], y.w, a[3] * xv);
            __builtin_nontemporal_store(y, (f4_t*)(op + (size_t)(st * ST_ + j) * DE_));
        }
    }
}

// Fallback if workspace is too small: one thread per chain, full serial scan.
__global__ __launch_bounds__(256) void ema_naive(const float* __restrict__ x,
                                                 const float* __restrict__ ld,
                                                 float* __restrict__ out) {
    const int chain = blockIdx.x * 256 + threadIdx.x;  // 0..4095
    const int d = chain >> 3;
    const int e = chain & 7;
    const float a = sigmoidf_(ld[e]);
    const float b = 1.0f - a;
    float y = x[d];
    for (int l = 0; l < L_; ++l) {
        y = fmaf(b, y, a * x[(size_t)l * D_ + d]);
        out[(size_t)l * DE_ + chain] = y;
    }
}

extern "C" void kernel_launch(void* const* d_in, const int* in_sizes, int n_in,
                              void* d_out, int out_size, void* d_ws, size_t ws_size,
                              hipStream_t stream) {
    const float* x  = (const float*)d_in[0];
    const float* ld = (const float*)d_in[1];
    float* out = (float*)d_out;

    // contrib: C_ rows; states: C_+1 rows
    const size_t need = (size_t)(2 * C_ + 1) * DE_ * sizeof(float);
    if (ws_size >= need) {
        float* contrib = (float*)d_ws;
        float* states  = contrib + (size_t)C_ * DE_;
        ema_pass1<<<C_, 1024, 0, stream>>>(x, ld, contrib);
        ema_pass2<<<DE_ / 256, 256, 0, stream>>>(x, ld, contrib, states);
        ema_pass3<<<C_, 1024, 0, stream>>>(x, ld, states, out);
    } else {
        ema_naive<<<DE_ / 256, 256, 0, stream>>>(x, ld, out);
    }
}